// Round 2
// baseline (405.791 us; speedup 1.0000x reference)
//
#include <hip/hip_runtime.h>
#include <stdint.h>

#define B_ 2
#define S_ 2048
#define E_ 1024
#define H_ 16
#define D_ 64
#define M_ (B_*S_)      // 4096 rows in the GEMM view
#define HALF_W 128

typedef float  f32x4  __attribute__((ext_vector_type(4)));
typedef short  s16x8  __attribute__((ext_vector_type(8)));
typedef __bf16 bf16x8 __attribute__((ext_vector_type(8)));

__device__ __forceinline__ f32x4 MFMA(bf16x8 a, bf16x8 b, f32x4 c) {
    return __builtin_amdgcn_mfma_f32_16x16x32_bf16(a, b, c, 0, 0, 0);
}

__device__ __forceinline__ unsigned short f2bf(float f) {
    union { float f; unsigned int u; } x; x.f = f;
    unsigned int u = x.u + 0x7FFFu + ((x.u >> 16) & 1u);
    return (unsigned short)(u >> 16);
}

__device__ __forceinline__ void cvt_store8(unsigned short* dst, f32x4 a, f32x4 b) {
    s16x8 h;
    h[0]=(short)f2bf(a[0]); h[1]=(short)f2bf(a[1]); h[2]=(short)f2bf(a[2]); h[3]=(short)f2bf(a[3]);
    h[4]=(short)f2bf(b[0]); h[5]=(short)f2bf(b[1]); h[6]=(short)f2bf(b[2]); h[7]=(short)f2bf(b[3]);
    *(s16x8*)dst = h;
}

// ---------------------------------------------------------------------------
// Kernel 1: QKV projections. C = X @ W^T + b   (M=4096, N=1024, K=1024)
// grid = (N/64, M/64, 3); block = 256. Output bf16 in (B*H, S, D) layout.
// ---------------------------------------------------------------------------
__global__ __launch_bounds__(256) void qkv_kernel(
    const float* __restrict__ query, const float* __restrict__ key,
    const float* __restrict__ value,
    const float* __restrict__ Wq, const float* __restrict__ bq,
    const float* __restrict__ Wk, const float* __restrict__ bk,
    const float* __restrict__ Wv, const float* __restrict__ bv,
    unsigned short* __restrict__ ws_qkv)
{
    const int z = blockIdx.z;
    const float* X    = (z==0) ? query : (z==1) ? key : value;
    const float* W    = (z==0) ? Wq    : (z==1) ? Wk  : Wv;
    const float* bias = (z==0) ? bq    : (z==1) ? bk  : bv;
    unsigned short* dst = ws_qkv + (size_t)z * ((size_t)M_ * E_);

    __shared__ __align__(16) unsigned short As[64 * 40];  // 64 rows x 32 k, pad->40
    __shared__ __align__(16) unsigned short Bs[64 * 40];

    const int t    = threadIdx.x;
    const int lane = t & 63;
    const int w    = t >> 6;
    const int quad = lane >> 4;
    const int l16  = lane & 15;
    const int rowBase = blockIdx.y * 64;
    const int nBase   = blockIdx.x * 64;
    const int m0 = (w & 1) * 32;
    const int n0 = (w >> 1) * 32;

    const int srow = t >> 2;      // 0..63
    const int scg  = t & 3;       // 0..3  (8 floats each)

    f32x4 acc[2][2] = {};

    for (int kk = 0; kk < 1024; kk += 32) {
        // stage A (fp32 -> bf16)
        {
            const float* pa = X + (size_t)(rowBase + srow) * 1024 + kk + scg * 8;
            f32x4 a0 = *(const f32x4*)pa;
            f32x4 a1 = *(const f32x4*)(pa + 4);
            cvt_store8(&As[srow * 40 + scg * 8], a0, a1);
            const float* pb = W + (size_t)(nBase + srow) * 1024 + kk + scg * 8;
            f32x4 b0 = *(const f32x4*)pb;
            f32x4 b1 = *(const f32x4*)(pb + 4);
            cvt_store8(&Bs[srow * 40 + scg * 8], b0, b1);
        }
        __syncthreads();
        bf16x8 a0 = *(const bf16x8*)&As[(m0 +      l16) * 40 + quad * 8];
        bf16x8 a1 = *(const bf16x8*)&As[(m0 + 16 + l16) * 40 + quad * 8];
        bf16x8 b0 = *(const bf16x8*)&Bs[(n0 +      l16) * 40 + quad * 8];
        bf16x8 b1 = *(const bf16x8*)&Bs[(n0 + 16 + l16) * 40 + quad * 8];
        acc[0][0] = MFMA(a0, b0, acc[0][0]);
        acc[0][1] = MFMA(a0, b1, acc[0][1]);
        acc[1][0] = MFMA(a1, b0, acc[1][0]);
        acc[1][1] = MFMA(a1, b1, acc[1][1]);
        __syncthreads();
    }

    // epilogue: bias add, permute to (b,h,s,d), bf16 store
    #pragma unroll
    for (int im = 0; im < 2; im++)
      #pragma unroll
      for (int in = 0; in < 2; in++)
        #pragma unroll
        for (int r = 0; r < 4; r++) {
            int row = rowBase + m0 + im * 16 + quad * 4 + r;   // b*S+s
            int col = nBase   + n0 + in * 16 + l16;            // h*64+d
            float v = acc[im][in][r] + bias[col];
            int b = row >> 11, s = row & 2047;
            int h = col >> 6,  d = col & 63;
            dst[(((size_t)(b * H_ + h)) * S_ + s) * D_ + d] = f2bf(v);
        }
}

// ---------------------------------------------------------------------------
// Kernel 2: fused attention, online softmax. grid = (S/64, B*H); block = 256.
// Each wave owns 16 Q rows; K/V tiles of 32 keys staged in LDS.
// ---------------------------------------------------------------------------
__global__ __launch_bounds__(256) void attn_kernel(
    const unsigned short* __restrict__ ws_qkv,
    unsigned short* __restrict__ attn_ws)
{
    const int bh = blockIdx.y;            // 0..31
    const int b  = bh >> 4, h = bh & 15;
    const int qbase = blockIdx.x * 64;
    const int t    = threadIdx.x;
    const int w    = t >> 6;
    const int lane = t & 63;
    const int quad = lane >> 4;
    const int l16  = lane & 15;

    const unsigned short* q = ws_qkv + (size_t)bh * (S_ * D_);
    const unsigned short* k = ws_qkv + (size_t)(M_) * E_     + (size_t)bh * (S_ * D_);
    const unsigned short* v = ws_qkv + (size_t)(2 * M_) * E_ + (size_t)bh * (S_ * D_);

    __shared__ __align__(16) unsigned short Ks [32 * 72];   // 32 keys x 64 d, pad->72
    __shared__ __align__(16) unsigned short VTs[64 * 40];   // 64 d x 32 keys, pad->40
    __shared__ __align__(16) unsigned short Ps [4][16 * 40];// per-wave P tile 16x32, pad->40

    const int qrow = qbase + w * 16 + l16;
    bf16x8 aq0 = *(const bf16x8*)&q[(size_t)qrow * 64 +      quad * 8];
    bf16x8 aq1 = *(const bf16x8*)&q[(size_t)qrow * 64 + 32 + quad * 8];

    float mrun[4], lrun[4];
    f32x4 O[4] = {};
    #pragma unroll
    for (int r = 0; r < 4; r++) { mrun[r] = -1e30f; lrun[r] = 0.f; }

    const float SCL      = 0.125f * 1.44269504089f;  // scale * log2(e)
    const float MASK_ADD = 1.44269504089f;           // +1 (outside band) * log2(e)

    for (int kt = 0; kt < S_; kt += 32) {
        // stage K tile (row-major) and V tile transposed
        {
            int row = t >> 3, cg = t & 7;
            *(s16x8*)&Ks[row * 72 + cg * 8] =
                *(const s16x8*)&k[(size_t)(kt + row) * 64 + cg * 8];
            int key = t & 31, dg = t >> 5;
            s16x8 vv = *(const s16x8*)&v[(size_t)(kt + key) * 64 + dg * 8];
            #pragma unroll
            for (int i = 0; i < 8; i++) VTs[(dg * 8 + i) * 40 + key] = (unsigned short)vv[i];
        }
        __syncthreads();

        // S = Q K^T  (two 16-key subtiles)
        f32x4 sc[2];
        #pragma unroll
        for (int sub = 0; sub < 2; sub++) {
            bf16x8 bk0 = *(const bf16x8*)&Ks[(sub * 16 + l16) * 72 +      quad * 8];
            bf16x8 bk1 = *(const bf16x8*)&Ks[(sub * 16 + l16) * 72 + 32 + quad * 8];
            f32x4 zz = {};
            zz = MFMA(aq0, bk0, zz);
            zz = MFMA(aq1, bk1, zz);
            sc[sub] = zz;
        }

        // scale + additive mask, in log2 domain
        const int i0 = qbase + w * 16 + quad * 4;
        #pragma unroll
        for (int sub = 0; sub < 2; sub++) {
            int j = kt + sub * 16 + l16;
            #pragma unroll
            for (int r = 0; r < 4; r++) {
                int di = i0 + r - j; di = di < 0 ? -di : di;
                sc[sub][r] = sc[sub][r] * SCL + (di <= HALF_W ? 0.f : MASK_ADD);
            }
        }

        // row max across the 16 lanes of the quad-group
        float rowm[4];
        #pragma unroll
        for (int r = 0; r < 4; r++) rowm[r] = fmaxf(sc[0][r], sc[1][r]);
        #pragma unroll
        for (int mm = 1; mm < 16; mm <<= 1)
            #pragma unroll
            for (int r = 0; r < 4; r++)
                rowm[r] = fmaxf(rowm[r], __shfl_xor(rowm[r], mm, 16));

        // online softmax update
        float p0[4], p1[4], alpha[4], rs[4];
        #pragma unroll
        for (int r = 0; r < 4; r++) {
            float mn = fmaxf(mrun[r], rowm[r]);
            alpha[r] = exp2f(mrun[r] - mn);
            mrun[r]  = mn;
            p0[r] = exp2f(sc[0][r] - mn);
            p1[r] = exp2f(sc[1][r] - mn);
            rs[r] = p0[r] + p1[r];
        }
        #pragma unroll
        for (int mm = 1; mm < 16; mm <<= 1)
            #pragma unroll
            for (int r = 0; r < 4; r++)
                rs[r] += __shfl_xor(rs[r], mm, 16);
        #pragma unroll
        for (int r = 0; r < 4; r++) {
            lrun[r] = lrun[r] * alpha[r] + rs[r];
            #pragma unroll
            for (int dt = 0; dt < 4; dt++) O[dt][r] *= alpha[r];
        }

        // P: C/D layout -> LDS -> A-operand layout (bf16)
        #pragma unroll
        for (int r = 0; r < 4; r++) {
            Ps[w][(quad * 4 + r) * 40 +      l16] = f2bf(p0[r]);
            Ps[w][(quad * 4 + r) * 40 + 16 + l16] = f2bf(p1[r]);
        }
        __syncthreads();

        bf16x8 aP = *(const bf16x8*)&Ps[w][l16 * 40 + quad * 8];
        #pragma unroll
        for (int dt = 0; dt < 4; dt++) {
            bf16x8 bV = *(const bf16x8*)&VTs[(dt * 16 + l16) * 40 + quad * 8];
            O[dt] = MFMA(aP, bV, O[dt]);
        }
        __syncthreads();
    }

    // epilogue: normalize, store bf16 to (B,S,E)
    #pragma unroll
    for (int dt = 0; dt < 4; dt++)
        #pragma unroll
        for (int r = 0; r < 4; r++) {
            float oo = O[dt][r] / lrun[r];
            int srow = qbase + w * 16 + quad * 4 + r;
            int col  = h * 64 + dt * 16 + l16;
            attn_ws[((size_t)(b * S_ + srow)) * E_ + col] = f2bf(oo);
        }
}

// ---------------------------------------------------------------------------
// Kernel 3: output projection. out = A(bf16) @ Wo^T + bo  (fp32 out)
// grid = (N/64, M/64); block = 256.
// ---------------------------------------------------------------------------
__global__ __launch_bounds__(256) void oproj_kernel(
    const unsigned short* __restrict__ Aattn, const float* __restrict__ Wo,
    const float* __restrict__ bo, float* __restrict__ out)
{
    __shared__ __align__(16) unsigned short As[64 * 40];
    __shared__ __align__(16) unsigned short Bs[64 * 40];

    const int t    = threadIdx.x;
    const int lane = t & 63;
    const int w    = t >> 6;
    const int quad = lane >> 4;
    const int l16  = lane & 15;
    const int rowBase = blockIdx.y * 64;
    const int nBase   = blockIdx.x * 64;
    const int m0 = (w & 1) * 32;
    const int n0 = (w >> 1) * 32;

    const int srow = t >> 2;
    const int scg  = t & 3;

    f32x4 acc[2][2] = {};

    for (int kk = 0; kk < 1024; kk += 32) {
        {
            // A already bf16
            *(s16x8*)&As[srow * 40 + scg * 8] =
                *(const s16x8*)&Aattn[(size_t)(rowBase + srow) * 1024 + kk + scg * 8];
            const float* pb = Wo + (size_t)(nBase + srow) * 1024 + kk + scg * 8;
            f32x4 b0 = *(const f32x4*)pb;
            f32x4 b1 = *(const f32x4*)(pb + 4);
            cvt_store8(&Bs[srow * 40 + scg * 8], b0, b1);
        }
        __syncthreads();
        bf16x8 a0 = *(const bf16x8*)&As[(m0 +      l16) * 40 + quad * 8];
        bf16x8 a1 = *(const bf16x8*)&As[(m0 + 16 + l16) * 40 + quad * 8];
        bf16x8 b0 = *(const bf16x8*)&Bs[(n0 +      l16) * 40 + quad * 8];
        bf16x8 b1 = *(const bf16x8*)&Bs[(n0 + 16 + l16) * 40 + quad * 8];
        acc[0][0] = MFMA(a0, b0, acc[0][0]);
        acc[0][1] = MFMA(a0, b1, acc[0][1]);
        acc[1][0] = MFMA(a1, b0, acc[1][0]);
        acc[1][1] = MFMA(a1, b1, acc[1][1]);
        __syncthreads();
    }

    #pragma unroll
    for (int im = 0; im < 2; im++)
      #pragma unroll
      for (int in = 0; in < 2; in++)
        #pragma unroll
        for (int r = 0; r < 4; r++) {
            int row = rowBase + m0 + im * 16 + quad * 4 + r;
            int col = nBase   + n0 + in * 16 + l16;
            out[(size_t)row * 1024 + col] = acc[im][in][r] + bo[col];
        }
}

// ---------------------------------------------------------------------------
extern "C" void kernel_launch(void* const* d_in, const int* in_sizes, int n_in,
                              void* d_out, int out_size, void* d_ws, size_t ws_size,
                              hipStream_t stream) {
    const float* query = (const float*)d_in[0];
    const float* key_  = (const float*)d_in[1];
    const float* value = (const float*)d_in[2];
    const float* Wq = (const float*)d_in[3];
    const float* bq = (const float*)d_in[4];
    const float* Wk = (const float*)d_in[5];
    const float* bk = (const float*)d_in[6];
    const float* Wv = (const float*)d_in[7];
    const float* bv = (const float*)d_in[8];
    const float* Wo = (const float*)d_in[9];
    const float* bo = (const float*)d_in[10];

    unsigned short* ws_qkv  = (unsigned short*)d_ws;                 // 3 * 8 MB bf16
    unsigned short* attn_ws = ws_qkv + (size_t)3 * M_ * E_;          // 8 MB bf16
    float* out = (float*)d_out;

    dim3 g1(E_ / 64, M_ / 64, 3);
    qkv_kernel<<<g1, 256, 0, stream>>>(query, key_, value,
                                       Wq, bq, Wk, bk, Wv, bv, ws_qkv);
    dim3 g2(S_ / 64, B_ * H_);
    attn_kernel<<<g2, 256, 0, stream>>>(ws_qkv, attn_ws);
    dim3 g3(E_ / 64, M_ / 64);
    oproj_kernel<<<g3, 256, 0, stream>>>(attn_ws, Wo, bo, out);
}

// Round 3
// 314.358 us; speedup vs baseline: 1.2909x; 1.2909x over previous
//
#include <hip/hip_runtime.h>
#include <stdint.h>

#define B_ 2
#define S_ 2048
#define E_ 1024
#define H_ 16
#define D_ 64
#define M_ (B_*S_)      // 4096 rows in the GEMM view
#define HALF_W 128

typedef float  f32x4  __attribute__((ext_vector_type(4)));
typedef short  s16x8  __attribute__((ext_vector_type(8)));
typedef __bf16 bf16x8 __attribute__((ext_vector_type(8)));

__device__ __forceinline__ f32x4 MFMA(bf16x8 a, bf16x8 b, f32x4 c) {
    return __builtin_amdgcn_mfma_f32_16x16x32_bf16(a, b, c, 0, 0, 0);
}

__device__ __forceinline__ unsigned short f2bf(float f) {
    union { float f; unsigned int u; } x; x.f = f;
    unsigned int u = x.u + 0x7FFFu + ((x.u >> 16) & 1u);
    return (unsigned short)(u >> 16);
}

__device__ __forceinline__ void cvt_store8(unsigned short* dst, f32x4 a, f32x4 b) {
    s16x8 h;
    h[0]=(short)f2bf(a[0]); h[1]=(short)f2bf(a[1]); h[2]=(short)f2bf(a[2]); h[3]=(short)f2bf(a[3]);
    h[4]=(short)f2bf(b[0]); h[5]=(short)f2bf(b[1]); h[6]=(short)f2bf(b[2]); h[7]=(short)f2bf(b[3]);
    *(s16x8*)dst = h;
}

// ---------------------------------------------------------------------------
// Kernel 1: QKV projections. C = X @ W^T + b   (M=4096, N=1024, K=1024)
// grid = (N/64, M/64, 3); block = 256. Output bf16 in (B*H, S, D) layout.
// ---------------------------------------------------------------------------
__global__ __launch_bounds__(256) void qkv_kernel(
    const float* __restrict__ query, const float* __restrict__ key,
    const float* __restrict__ value,
    const float* __restrict__ Wq, const float* __restrict__ bq,
    const float* __restrict__ Wk, const float* __restrict__ bk,
    const float* __restrict__ Wv, const float* __restrict__ bv,
    unsigned short* __restrict__ ws_qkv)
{
    const int z = blockIdx.z;
    const float* X    = (z==0) ? query : (z==1) ? key : value;
    const float* W    = (z==0) ? Wq    : (z==1) ? Wk  : Wv;
    const float* bias = (z==0) ? bq    : (z==1) ? bk  : bv;
    unsigned short* dst = ws_qkv + (size_t)z * ((size_t)M_ * E_);

    __shared__ __align__(16) unsigned short As[64 * 40];  // 64 rows x 32 k, pad->40
    __shared__ __align__(16) unsigned short Bs[64 * 40];

    const int t    = threadIdx.x;
    const int lane = t & 63;
    const int w    = t >> 6;
    const int quad = lane >> 4;
    const int l16  = lane & 15;
    const int rowBase = blockIdx.y * 64;
    const int nBase   = blockIdx.x * 64;
    const int m0 = (w & 1) * 32;
    const int n0 = (w >> 1) * 32;

    const int srow = t >> 2;      // 0..63
    const int scg  = t & 3;       // 0..3  (8 floats each)

    f32x4 acc[2][2] = {};

    for (int kk = 0; kk < 1024; kk += 32) {
        // stage A (fp32 -> bf16)
        {
            const float* pa = X + (size_t)(rowBase + srow) * 1024 + kk + scg * 8;
            f32x4 a0 = *(const f32x4*)pa;
            f32x4 a1 = *(const f32x4*)(pa + 4);
            cvt_store8(&As[srow * 40 + scg * 8], a0, a1);
            const float* pb = W + (size_t)(nBase + srow) * 1024 + kk + scg * 8;
            f32x4 b0 = *(const f32x4*)pb;
            f32x4 b1 = *(const f32x4*)(pb + 4);
            cvt_store8(&Bs[srow * 40 + scg * 8], b0, b1);
        }
        __syncthreads();
        bf16x8 a0 = *(const bf16x8*)&As[(m0 +      l16) * 40 + quad * 8];
        bf16x8 a1 = *(const bf16x8*)&As[(m0 + 16 + l16) * 40 + quad * 8];
        bf16x8 b0 = *(const bf16x8*)&Bs[(n0 +      l16) * 40 + quad * 8];
        bf16x8 b1 = *(const bf16x8*)&Bs[(n0 + 16 + l16) * 40 + quad * 8];
        acc[0][0] = MFMA(a0, b0, acc[0][0]);
        acc[0][1] = MFMA(a0, b1, acc[0][1]);
        acc[1][0] = MFMA(a1, b0, acc[1][0]);
        acc[1][1] = MFMA(a1, b1, acc[1][1]);
        __syncthreads();
    }

    // epilogue: bias add, permute to (b,h,s,d), bf16 store
    #pragma unroll
    for (int im = 0; im < 2; im++)
      #pragma unroll
      for (int in = 0; in < 2; in++)
        #pragma unroll
        for (int r = 0; r < 4; r++) {
            int row = rowBase + m0 + im * 16 + quad * 4 + r;   // b*S+s
            int col = nBase   + n0 + in * 16 + l16;            // h*64+d
            float v = acc[im][in][r] + bias[col];
            int b = row >> 11, s = row & 2047;
            int h = col >> 6,  d = col & 63;
            dst[(((size_t)(b * H_ + h)) * S_ + s) * D_ + d] = f2bf(v);
        }
}

// ---------------------------------------------------------------------------
// Kernel 2: fused attention. grid = (S/64, B*H); block = 256 (4 waves).
// S^T = K·Q^T trick: C/D layout puts query on lane&15 -> P is already in
// A-operand slots for PV (with a custom k-permutation matched by VT layout).
// No running max (additive mask, scores bounded); per-lane partial denom.
// ---------------------------------------------------------------------------
__global__ __launch_bounds__(256) void attn_kernel(
    const unsigned short* __restrict__ ws_qkv,
    unsigned short* __restrict__ attn_ws)
{
    const int bh = blockIdx.y;            // 0..31
    const int b  = bh >> 4, h = bh & 15;
    const int qbase = blockIdx.x * 64;
    const int t    = threadIdx.x;
    const int w    = t >> 6;
    const int lane = t & 63;
    const int quad = lane >> 4;
    const int l16  = lane & 15;

    const unsigned short* q = ws_qkv + (size_t)bh * (S_ * D_);
    const unsigned short* k = ws_qkv + (size_t)(M_) * E_     + (size_t)bh * (S_ * D_);
    const unsigned short* v = ws_qkv + (size_t)(2 * M_) * E_ + (size_t)bh * (S_ * D_);

    __shared__ __align__(16) unsigned short Ks[64 * 72];  // 64 keys x 64 d (pad 72)
    __shared__ __align__(16) unsigned short VT[64 * 72];  // 64 d x 64 perm-slots (pad 72)

    const int qi = qbase + w * 16 + l16;    // this lane's query row
    bf16x8 aq0 = *(const bf16x8*)&q[(size_t)qi * 64 +      quad * 8];
    bf16x8 aq1 = *(const bf16x8*)&q[(size_t)qi * 64 + 32 + quad * 8];

    f32x4 O[4] = {};
    float lsum = 0.f;

    const float SCL  = 0.125f * 1.44269504089f;  // scale * log2(e)
    const float MADD = 1.44269504089f;           // +1 outside band, * log2(e)

    // staging geometry (256 threads)
    const int srow = t >> 2;            // 0..63 : key row for Ks
    const int scg  = (t & 3) * 16;      // dim start (two b128)
    const int vkey = t & 63;            // key for VT
    const int vdg  = (t >> 6) * 8;      // dim start (pass0; pass1 = +32)
    // permuted slot: key -> g*32 + q*8 + h*4 + r  (matches PV A-frag packing)
    const int vsub = vkey >> 4;
    const int vslot = (vsub >> 1) * 32 + (((vkey >> 2) & 3) * 8) + ((vsub & 1) * 4) + (vkey & 3);

    for (int kt = 0; kt < S_; kt += 64) {
        __syncthreads();   // previous tile's LDS reads complete
        // stage K (row-major)
        *(s16x8*)&Ks[srow * 72 + scg]     = *(const s16x8*)&k[(size_t)(kt + srow) * 64 + scg];
        *(s16x8*)&Ks[srow * 72 + scg + 8] = *(const s16x8*)&k[(size_t)(kt + srow) * 64 + scg + 8];
        // stage V transposed into permuted-slot layout
        {
            s16x8 v0 = *(const s16x8*)&v[(size_t)(kt + vkey) * 64 + vdg];
            s16x8 v1 = *(const s16x8*)&v[(size_t)(kt + vkey) * 64 + vdg + 32];
            #pragma unroll
            for (int i = 0; i < 8; i++) VT[(vdg +      i) * 72 + vslot] = (unsigned short)v0[i];
            #pragma unroll
            for (int i = 0; i < 8; i++) VT[(vdg + 32 + i) * 72 + vslot] = (unsigned short)v1[i];
        }
        __syncthreads();

        // S^T = K Q^T : lane holds S^T[key=kt+sub*16+quad*4+r][query=qi]
        f32x4 p[4];
        #pragma unroll
        for (int sub = 0; sub < 4; sub++) {
            bf16x8 bk0 = *(const bf16x8*)&Ks[(sub * 16 + l16) * 72 +      quad * 8];
            bf16x8 bk1 = *(const bf16x8*)&Ks[(sub * 16 + l16) * 72 + 32 + quad * 8];
            f32x4 zz = {};
            zz = MFMA(bk0, aq0, zz);
            zz = MFMA(bk1, aq1, zz);
            const int jb = kt + sub * 16 + quad * 4;   // key base for this sub
            #pragma unroll
            for (int r = 0; r < 4; r++) {
                int di = qi - (jb + r); di = di < 0 ? -di : di;
                float e = zz[r] * SCL + (di <= HALF_W ? 0.f : MADD);
                p[sub][r] = exp2f(e);
                lsum += p[sub][r];
            }
        }

        // PV: two K=32 MFMAs per d-tile, P packed per custom k-permutation
        #pragma unroll
        for (int g = 0; g < 2; g++) {
            bf16x8 aP;
            #pragma unroll
            for (int j = 0; j < 4; j++) {
                aP[j]     = (__bf16)p[2 * g][j];
                aP[4 + j] = (__bf16)p[2 * g + 1][j];
            }
            #pragma unroll
            for (int dt = 0; dt < 4; dt++) {
                bf16x8 bV = *(const bf16x8*)&VT[(dt * 16 + l16) * 72 + g * 32 + quad * 8];
                O[dt] = MFMA(aP, bV, O[dt]);
            }
        }
    }

    // final denominator: reduce across the 4 quad-groups (same l16 = same query)
    lsum += __shfl_xor(lsum, 16);
    lsum += __shfl_xor(lsum, 32);
    float lq[4];
    #pragma unroll
    for (int r = 0; r < 4; r++) lq[r] = __shfl(lsum, quad * 4 + r, 16);

    // epilogue: O lane holds O[query=w*16+quad*4+r][d=dt*16+l16]
    #pragma unroll
    for (int dt = 0; dt < 4; dt++)
        #pragma unroll
        for (int r = 0; r < 4; r++) {
            float oo = O[dt][r] / lq[r];
            int srow2 = qbase + w * 16 + quad * 4 + r;
            int col   = h * 64 + dt * 16 + l16;
            attn_ws[((size_t)(b * S_ + srow2)) * E_ + col] = f2bf(oo);
        }
}

// ---------------------------------------------------------------------------
// Kernel 3: output projection. out = A(bf16) @ Wo^T + bo  (fp32 out)
// grid = (N/64, M/64); block = 256.
// ---------------------------------------------------------------------------
__global__ __launch_bounds__(256) void oproj_kernel(
    const unsigned short* __restrict__ Aattn, const float* __restrict__ Wo,
    const float* __restrict__ bo, float* __restrict__ out)
{
    __shared__ __align__(16) unsigned short As[64 * 40];
    __shared__ __align__(16) unsigned short Bs[64 * 40];

    const int t    = threadIdx.x;
    const int lane = t & 63;
    const int w    = t >> 6;
    const int quad = lane >> 4;
    const int l16  = lane & 15;
    const int rowBase = blockIdx.y * 64;
    const int nBase   = blockIdx.x * 64;
    const int m0 = (w & 1) * 32;
    const int n0 = (w >> 1) * 32;

    const int srow = t >> 2;
    const int scg  = t & 3;

    f32x4 acc[2][2] = {};

    for (int kk = 0; kk < 1024; kk += 32) {
        {
            // A already bf16
            *(s16x8*)&As[srow * 40 + scg * 8] =
                *(const s16x8*)&Aattn[(size_t)(rowBase + srow) * 1024 + kk + scg * 8];
            const float* pb = Wo + (size_t)(nBase + srow) * 1024 + kk + scg * 8;
            f32x4 b0 = *(const f32x4*)pb;
            f32x4 b1 = *(const f32x4*)(pb + 4);
            cvt_store8(&Bs[srow * 40 + scg * 8], b0, b1);
        }
        __syncthreads();
        bf16x8 a0 = *(const bf16x8*)&As[(m0 +      l16) * 40 + quad * 8];
        bf16x8 a1 = *(const bf16x8*)&As[(m0 + 16 + l16) * 40 + quad * 8];
        bf16x8 b0 = *(const bf16x8*)&Bs[(n0 +      l16) * 40 + quad * 8];
        bf16x8 b1 = *(const bf16x8*)&Bs[(n0 + 16 + l16) * 40 + quad * 8];
        acc[0][0] = MFMA(a0, b0, acc[0][0]);
        acc[0][1] = MFMA(a0, b1, acc[0][1]);
        acc[1][0] = MFMA(a1, b0, acc[1][0]);
        acc[1][1] = MFMA(a1, b1, acc[1][1]);
        __syncthreads();
    }

    #pragma unroll
    for (int im = 0; im < 2; im++)
      #pragma unroll
      for (int in = 0; in < 2; in++)
        #pragma unroll
        for (int r = 0; r < 4; r++) {
            int row = rowBase + m0 + im * 16 + quad * 4 + r;
            int col = nBase   + n0 + in * 16 + l16;
            out[(size_t)row * 1024 + col] = acc[im][in][r] + bo[col];
        }
}

// ---------------------------------------------------------------------------
extern "C" void kernel_launch(void* const* d_in, const int* in_sizes, int n_in,
                              void* d_out, int out_size, void* d_ws, size_t ws_size,
                              hipStream_t stream) {
    const float* query = (const float*)d_in[0];
    const float* key_  = (const float*)d_in[1];
    const float* value = (const float*)d_in[2];
    const float* Wq = (const float*)d_in[3];
    const float* bq = (const float*)d_in[4];
    const float* Wk = (const float*)d_in[5];
    const float* bk = (const float*)d_in[6];
    const float* Wv = (const float*)d_in[7];
    const float* bv = (const float*)d_in[8];
    const float* Wo = (const float*)d_in[9];
    const float* bo = (const float*)d_in[10];

    unsigned short* ws_qkv  = (unsigned short*)d_ws;                 // 3 * 8 MB bf16
    unsigned short* attn_ws = ws_qkv + (size_t)3 * M_ * E_;          // 8 MB bf16
    float* out = (float*)d_out;

    dim3 g1(E_ / 64, M_ / 64, 3);
    qkv_kernel<<<g1, 256, 0, stream>>>(query, key_, value,
                                       Wq, bq, Wk, bk, Wv, bv, ws_qkv);
    dim3 g2(S_ / 64, B_ * H_);
    attn_kernel<<<g2, 256, 0, stream>>>(ws_qkv, attn_ws);
    dim3 g3(E_ / 64, M_ / 64);
    oproj_kernel<<<g3, 256, 0, stream>>>(attn_ws, Wo, bo, out);
}

// Round 4
// 272.035 us; speedup vs baseline: 1.4917x; 1.1556x over previous
//
#include <hip/hip_runtime.h>
#include <stdint.h>

#define B_ 2
#define S_ 2048
#define E_ 1024
#define H_ 16
#define D_ 64
#define M_ (B_*S_)              // 4096
#define PROJ_ (M_*E_)           // 4194304 u16 elements per projection
#define HALF_W 128

typedef float  f32x4  __attribute__((ext_vector_type(4)));
typedef short  s16x8  __attribute__((ext_vector_type(8)));
typedef __bf16 bf16x8 __attribute__((ext_vector_type(8)));

__device__ __forceinline__ f32x4 MFMA(bf16x8 a, bf16x8 b, f32x4 c) {
    return __builtin_amdgcn_mfma_f32_16x16x32_bf16(a, b, c, 0, 0, 0);
}

__device__ __forceinline__ unsigned short f2bf(float f) {
    union { float f; unsigned int u; } x; x.f = f;
    unsigned int u = x.u + 0x7FFFu + ((x.u >> 16) & 1u);
    return (unsigned short)(u >> 16);
}

__device__ __forceinline__ s16x8 cvt8(f32x4 a, f32x4 b) {
    s16x8 h;
    h[0]=(short)f2bf(a[0]); h[1]=(short)f2bf(a[1]); h[2]=(short)f2bf(a[2]); h[3]=(short)f2bf(a[3]);
    h[4]=(short)f2bf(b[0]); h[5]=(short)f2bf(b[1]); h[6]=(short)f2bf(b[2]); h[7]=(short)f2bf(b[3]);
    return h;
}

// ---------------------------------------------------------------------------
// Kernel 0: fp32 -> bf16 convert for the three X inputs.
// grid=(2048,3), block=256, 8 elems/thread.
// ---------------------------------------------------------------------------
__global__ __launch_bounds__(256) void cvt_kernel(
    const float* __restrict__ q, const float* __restrict__ k, const float* __restrict__ v,
    unsigned short* __restrict__ xq, unsigned short* __restrict__ xk,
    unsigned short* __restrict__ xv)
{
    const int z = blockIdx.y;
    const float* src = (z==0) ? q : (z==1) ? k : v;
    unsigned short* dst = (z==0) ? xq : (z==1) ? xk : xv;
    size_t i = ((size_t)blockIdx.x * 256 + threadIdx.x) * 8;
    f32x4 a = *(const f32x4*)(src + i);
    f32x4 b = *(const f32x4*)(src + i + 4);
    *(s16x8*)(dst + i) = cvt8(a, b);
}

// ---------------------------------------------------------------------------
// Kernel 1: QKV projections, 128x128 tile, BK=32, reg-double-buffered staging.
// A = X bf16 (pre-converted), B = W fp32 (converted at LDS-write time).
// Output: q,k row-major (bh,s,d); v transposed+slot-permuted (bh,d,keyslot).
// grid=(8,32,3), block=256.
// ---------------------------------------------------------------------------
__global__ __launch_bounds__(256) void qkv_kernel(
    const unsigned short* __restrict__ xq, const unsigned short* __restrict__ xk,
    const unsigned short* __restrict__ xv,
    const float* __restrict__ Wq, const float* __restrict__ bq,
    const float* __restrict__ Wk, const float* __restrict__ bk,
    const float* __restrict__ Wv, const float* __restrict__ bv,
    unsigned short* __restrict__ qkvout)
{
    const int z = blockIdx.z;
    const unsigned short* X = (z==0) ? xq : (z==1) ? xk : xv;
    const float* W    = (z==0) ? Wq : (z==1) ? Wk : Wv;
    const float* bias = (z==0) ? bq : (z==1) ? bk : bv;
    unsigned short* dst = qkvout + (size_t)z * PROJ_;

    __shared__ __align__(16) unsigned short As[128 * 32];
    __shared__ __align__(16) unsigned short Bs[128 * 32];

    const int t = threadIdx.x;
    const int lane = t & 63, w = t >> 6;
    const int quad = lane >> 4, l16 = lane & 15;
    const int wm = (w & 1) * 64, wn = (w >> 1) * 64;
    const int rowBase = blockIdx.y * 128, nBase = blockIdx.x * 128;

    // staging: thread t owns chunks {t, t+256}; chunk c: row=c>>2, kcol=(c&3)*8
    const int arow = t >> 2, akc = (t & 3) * 8;
    const unsigned short* gA = X + (size_t)(rowBase + arow) * E_ + akc;
    const float*          gB = W + (size_t)(nBase   + arow) * E_ + akc;

    f32x4 acc[4][4] = {};

    s16x8 pa0 = *(const s16x8*)gA;
    s16x8 pa1 = *(const s16x8*)(gA + (size_t)64 * E_);
    f32x4 pb0a = *(const f32x4*)gB;
    f32x4 pb0b = *(const f32x4*)(gB + 4);
    f32x4 pb1a = *(const f32x4*)(gB + (size_t)64 * E_);
    f32x4 pb1b = *(const f32x4*)(gB + (size_t)64 * E_ + 4);

    for (int kk = 0; kk < E_; kk += 32) {
        __syncthreads();
        *(s16x8*)&As[t * 8]         = pa0;
        *(s16x8*)&As[(t + 256) * 8] = pa1;
        *(s16x8*)&Bs[t * 8]         = cvt8(pb0a, pb0b);
        *(s16x8*)&Bs[(t + 256) * 8] = cvt8(pb1a, pb1b);
        __syncthreads();
        if (kk + 32 < E_) {
            int nk = kk + 32;
            pa0  = *(const s16x8*)(gA + nk);
            pa1  = *(const s16x8*)(gA + (size_t)64 * E_ + nk);
            pb0a = *(const f32x4*)(gB + nk);
            pb0b = *(const f32x4*)(gB + nk + 4);
            pb1a = *(const f32x4*)(gB + (size_t)64 * E_ + nk);
            pb1b = *(const f32x4*)(gB + (size_t)64 * E_ + nk + 4);
        }
        bf16x8 af[4], bfr[4];
        #pragma unroll
        for (int im = 0; im < 4; im++)
            af[im] = *(const bf16x8*)&As[(wm + im * 16 + l16) * 32 + quad * 8];
        #pragma unroll
        for (int in = 0; in < 4; in++)
            bfr[in] = *(const bf16x8*)&Bs[(wn + in * 16 + l16) * 32 + quad * 8];
        #pragma unroll
        for (int im = 0; im < 4; im++)
            #pragma unroll
            for (int in = 0; in < 4; in++)
                acc[im][in] = MFMA(af[im], bfr[in], acc[im][in]);
    }

    // epilogue: bias, permute, bf16 store (V transposed + slot-permuted)
    #pragma unroll
    for (int im = 0; im < 4; im++)
      #pragma unroll
      for (int in = 0; in < 4; in++) {
        int col = nBase + wn + in * 16 + l16;       // h*64+d
        float bb = bias[col];
        int h = col >> 6, d = col & 63;
        #pragma unroll
        for (int r = 0; r < 4; r++) {
            int row = rowBase + wm + im * 16 + quad * 4 + r;  // b*S+s
            float val = acc[im][in][r] + bb;
            int b = row >> 11, s = row & 2047;
            size_t base = ((size_t)(b * H_ + h)) * (S_ * D_);
            if (z < 2) {
                dst[base + (size_t)s * 64 + d] = f2bf(val);
            } else {
                int k6 = s & 63;
                int slot = ((k6 >> 5) & 1) * 32 + ((k6 >> 2) & 3) * 8
                         + ((k6 >> 4) & 1) * 4 + (k6 & 3);
                dst[base + (size_t)d * S_ + (s & ~63) + slot] = f2bf(val);
            }
        }
      }
}

// ---------------------------------------------------------------------------
// Kernel 2: fused attention. grid=(S/64, B*H), block=256 (4 waves, 16 q each).
// K^T trick (query on lane&15), no running max, per-lane denom, V pre-
// transposed/permuted in global so all staging is b128 vector ops.
// ---------------------------------------------------------------------------
__global__ __launch_bounds__(256) void attn_kernel(
    const unsigned short* __restrict__ qkvout,
    unsigned short* __restrict__ attnout)
{
    const int bh = blockIdx.y;
    const int b = bh >> 4, h = bh & 15;
    const int qbase = blockIdx.x * 64;
    const int t = threadIdx.x, w = t >> 6, lane = t & 63;
    const int quad = lane >> 4, l16 = lane & 15;

    const unsigned short* qg = qkvout + (size_t)bh * (S_ * D_);
    const unsigned short* kg = qkvout + (size_t)PROJ_     + (size_t)bh * (S_ * D_);
    const unsigned short* vT = qkvout + (size_t)2 * PROJ_ + (size_t)bh * (S_ * D_);

    __shared__ __align__(16) unsigned short Ks [64 * 72];
    __shared__ __align__(16) unsigned short VTs[64 * 72];

    const int qi = qbase + w * 16 + l16;
    bf16x8 aq0 = *(const bf16x8*)&qg[(size_t)qi * 64 +      quad * 8];
    bf16x8 aq1 = *(const bf16x8*)&qg[(size_t)qi * 64 + 32 + quad * 8];

    f32x4 O[4] = {};
    float lsum = 0.f;
    const float SCL  = 0.125f * 1.44269504089f;
    const float MADD = 1.44269504089f;

    // staging: thread t owns rows {t>>3, (t>>3)+32}, col chunk (t&7)*8
    const int srow = t >> 3, sdc = (t & 7) * 8;

    s16x8 kr0 = *(const s16x8*)&kg[(size_t)srow * 64 + sdc];
    s16x8 kr1 = *(const s16x8*)&kg[(size_t)(srow + 32) * 64 + sdc];
    s16x8 vr0 = *(const s16x8*)&vT[(size_t)srow * S_ + sdc];
    s16x8 vr1 = *(const s16x8*)&vT[(size_t)(srow + 32) * S_ + sdc];

    for (int kt = 0; kt < S_; kt += 64) {
        __syncthreads();
        *(s16x8*)&Ks [srow * 72 + sdc]        = kr0;
        *(s16x8*)&Ks [(srow + 32) * 72 + sdc] = kr1;
        *(s16x8*)&VTs[srow * 72 + sdc]        = vr0;
        *(s16x8*)&VTs[(srow + 32) * 72 + sdc] = vr1;
        __syncthreads();
        if (kt + 64 < S_) {
            kr0 = *(const s16x8*)&kg[(size_t)(kt + 64 + srow) * 64 + sdc];
            kr1 = *(const s16x8*)&kg[(size_t)(kt + 64 + srow + 32) * 64 + sdc];
            vr0 = *(const s16x8*)&vT[(size_t)srow * S_ + kt + 64 + sdc];
            vr1 = *(const s16x8*)&vT[(size_t)(srow + 32) * S_ + kt + 64 + sdc];
        }

        const int dq = qbase - kt;
        const bool mixed = (dq == 128 || dq == -128);
        const float cadd = (dq >= -64 && dq <= 64) ? 0.f : MADD;

        f32x4 p[4];
        #pragma unroll
        for (int sub = 0; sub < 4; sub++) {
            bf16x8 bk0 = *(const bf16x8*)&Ks[(sub * 16 + l16) * 72 +      quad * 8];
            bf16x8 bk1 = *(const bf16x8*)&Ks[(sub * 16 + l16) * 72 + 32 + quad * 8];
            f32x4 zz = {};
            zz = MFMA(bk0, aq0, zz);
            zz = MFMA(bk1, aq1, zz);
            if (!mixed) {
                #pragma unroll
                for (int r = 0; r < 4; r++) {
                    float pp = exp2f(fmaf(zz[r], SCL, cadd));
                    p[sub][r] = pp; lsum += pp;
                }
            } else {
                const int jb = kt + sub * 16 + quad * 4;
                #pragma unroll
                for (int r = 0; r < 4; r++) {
                    int di = qi - (jb + r); di = di < 0 ? -di : di;
                    float pp = exp2f(fmaf(zz[r], SCL, (di <= HALF_W ? 0.f : MADD)));
                    p[sub][r] = pp; lsum += pp;
                }
            }
        }

        #pragma unroll
        for (int g = 0; g < 2; g++) {
            bf16x8 aP;
            #pragma unroll
            for (int j = 0; j < 4; j++) {
                aP[j]     = (__bf16)p[2 * g][j];
                aP[4 + j] = (__bf16)p[2 * g + 1][j];
            }
            #pragma unroll
            for (int dt = 0; dt < 4; dt++) {
                bf16x8 bV = *(const bf16x8*)&VTs[(dt * 16 + l16) * 72 + g * 32 + quad * 8];
                O[dt] = MFMA(aP, bV, O[dt]);
            }
        }
    }

    lsum += __shfl_xor(lsum, 16);
    lsum += __shfl_xor(lsum, 32);
    float lq[4];
    #pragma unroll
    for (int r = 0; r < 4; r++) lq[r] = __shfl(lsum, quad * 4 + r, 16);

    #pragma unroll
    for (int dt = 0; dt < 4; dt++)
        #pragma unroll
        for (int r = 0; r < 4; r++) {
            float oo = O[dt][r] / lq[r];
            int srow2 = qbase + w * 16 + quad * 4 + r;
            int col   = h * 64 + dt * 16 + l16;
            attnout[((size_t)(b * S_ + srow2)) * E_ + col] = f2bf(oo);
        }
}

// ---------------------------------------------------------------------------
// Kernel 3: output projection, same 128x128 structure. A bf16, B=Wo fp32.
// grid=(8,32), block=256, fp32 out.
// ---------------------------------------------------------------------------
__global__ __launch_bounds__(256) void oproj_kernel(
    const unsigned short* __restrict__ Aattn, const float* __restrict__ Wo,
    const float* __restrict__ bo, float* __restrict__ out)
{
    __shared__ __align__(16) unsigned short As[128 * 32];
    __shared__ __align__(16) unsigned short Bs[128 * 32];

    const int t = threadIdx.x;
    const int lane = t & 63, w = t >> 6;
    const int quad = lane >> 4, l16 = lane & 15;
    const int wm = (w & 1) * 64, wn = (w >> 1) * 64;
    const int rowBase = blockIdx.y * 128, nBase = blockIdx.x * 128;

    const int arow = t >> 2, akc = (t & 3) * 8;
    const unsigned short* gA = Aattn + (size_t)(rowBase + arow) * E_ + akc;
    const float*          gB = Wo    + (size_t)(nBase   + arow) * E_ + akc;

    f32x4 acc[4][4] = {};

    s16x8 pa0 = *(const s16x8*)gA;
    s16x8 pa1 = *(const s16x8*)(gA + (size_t)64 * E_);
    f32x4 pb0a = *(const f32x4*)gB;
    f32x4 pb0b = *(const f32x4*)(gB + 4);
    f32x4 pb1a = *(const f32x4*)(gB + (size_t)64 * E_);
    f32x4 pb1b = *(const f32x4*)(gB + (size_t)64 * E_ + 4);

    for (int kk = 0; kk < E_; kk += 32) {
        __syncthreads();
        *(s16x8*)&As[t * 8]         = pa0;
        *(s16x8*)&As[(t + 256) * 8] = pa1;
        *(s16x8*)&Bs[t * 8]         = cvt8(pb0a, pb0b);
        *(s16x8*)&Bs[(t + 256) * 8] = cvt8(pb1a, pb1b);
        __syncthreads();
        if (kk + 32 < E_) {
            int nk = kk + 32;
            pa0  = *(const s16x8*)(gA + nk);
            pa1  = *(const s16x8*)(gA + (size_t)64 * E_ + nk);
            pb0a = *(const f32x4*)(gB + nk);
            pb0b = *(const f32x4*)(gB + nk + 4);
            pb1a = *(const f32x4*)(gB + (size_t)64 * E_ + nk);
            pb1b = *(const f32x4*)(gB + (size_t)64 * E_ + nk + 4);
        }
        bf16x8 af[4], bfr[4];
        #pragma unroll
        for (int im = 0; im < 4; im++)
            af[im] = *(const bf16x8*)&As[(wm + im * 16 + l16) * 32 + quad * 8];
        #pragma unroll
        for (int in = 0; in < 4; in++)
            bfr[in] = *(const bf16x8*)&Bs[(wn + in * 16 + l16) * 32 + quad * 8];
        #pragma unroll
        for (int im = 0; im < 4; im++)
            #pragma unroll
            for (int in = 0; in < 4; in++)
                acc[im][in] = MFMA(af[im], bfr[in], acc[im][in]);
    }

    #pragma unroll
    for (int im = 0; im < 4; im++)
      #pragma unroll
      for (int in = 0; in < 4; in++) {
        int col = nBase + wn + in * 16 + l16;
        float bb = bo[col];
        #pragma unroll
        for (int r = 0; r < 4; r++) {
            int row = rowBase + wm + im * 16 + quad * 4 + r;
            out[(size_t)row * E_ + col] = acc[im][in][r] + bb;
        }
      }
}

// ---------------------------------------------------------------------------
extern "C" void kernel_launch(void* const* d_in, const int* in_sizes, int n_in,
                              void* d_out, int out_size, void* d_ws, size_t ws_size,
                              hipStream_t stream) {
    const float* query = (const float*)d_in[0];
    const float* key_  = (const float*)d_in[1];
    const float* value = (const float*)d_in[2];
    const float* Wq = (const float*)d_in[3];
    const float* bq = (const float*)d_in[4];
    const float* Wk = (const float*)d_in[5];
    const float* bk = (const float*)d_in[6];
    const float* Wv = (const float*)d_in[7];
    const float* bv = (const float*)d_in[8];
    const float* Wo = (const float*)d_in[9];
    const float* bo = (const float*)d_in[10];

    // ws: [0..PROJ) Xv_bf16, later reused as attnout; [PROJ..4*PROJ) qkv out.
    // d_out doubles as Xq_bf16 + Xk_bf16 scratch until oproj overwrites it.
    unsigned short* ws      = (unsigned short*)d_ws;
    unsigned short* xv      = ws;
    unsigned short* attnout = ws;
    unsigned short* qkvout  = ws + (size_t)PROJ_;
    unsigned short* xq      = (unsigned short*)d_out;
    unsigned short* xk      = xq + (size_t)PROJ_;

    cvt_kernel<<<dim3(2048, 3), 256, 0, stream>>>(query, key_, value, xq, xk, xv);
    qkv_kernel<<<dim3(8, 32, 3), 256, 0, stream>>>(xq, xk, xv,
                                                   Wq, bq, Wk, bk, Wv, bv, qkvout);
    attn_kernel<<<dim3(32, 32), 256, 0, stream>>>(qkvout, attnout);
    oproj_kernel<<<dim3(8, 32), 256, 0, stream>>>(attnout, Wo, bo, (float*)d_out);
}

// Round 5
// 270.819 us; speedup vs baseline: 1.4984x; 1.0045x over previous
//
#include <hip/hip_runtime.h>
#include <stdint.h>

#define B_ 2
#define S_ 2048
#define E_ 1024
#define H_ 16
#define D_ 64
#define M_ (B_*S_)
#define PROJ_ ((size_t)M_*E_)
#define HALF_W 128

typedef float    f32x4 __attribute__((ext_vector_type(4)));
typedef short    s16x8 __attribute__((ext_vector_type(8)));
typedef __bf16   bf16x8 __attribute__((ext_vector_type(8)));
typedef _Float16 f16x8 __attribute__((ext_vector_type(8)));
typedef unsigned int u32x4 __attribute__((ext_vector_type(4)));

typedef const __attribute__((address_space(1))) void* gas_t;
typedef __attribute__((address_space(3))) void*       las_t;

__device__ __forceinline__ void gl16(const void* g, void* l) {
    __builtin_amdgcn_global_load_lds((gas_t)g, (las_t)l, 16, 0, 0);
}

__device__ __forceinline__ f32x4 MFMA(bf16x8 a, bf16x8 b, f32x4 c) {
    return __builtin_amdgcn_mfma_f32_16x16x32_bf16(a, b, c, 0, 0, 0);
}
__device__ __forceinline__ f32x4 MFMAH(f16x8 a, f16x8 b, f32x4 c) {
    return __builtin_amdgcn_mfma_f32_16x16x32_f16(a, b, c, 0, 0, 0);
}

__device__ __forceinline__ unsigned short f2bf(float f) {
    union { float f; unsigned int u; } x; x.f = f;
    unsigned int u = x.u + 0x7FFFu + ((x.u >> 16) & 1u);
    return (unsigned short)(u >> 16);
}

__device__ __forceinline__ s16x8 cvt8(f32x4 a, f32x4 b) {
    s16x8 h;
    h[0]=(short)f2bf(a[0]); h[1]=(short)f2bf(a[1]); h[2]=(short)f2bf(a[2]); h[3]=(short)f2bf(a[3]);
    h[4]=(short)f2bf(b[0]); h[5]=(short)f2bf(b[1]); h[6]=(short)f2bf(b[2]); h[7]=(short)f2bf(b[3]);
    return h;
}

// ---------------------------------------------------------------------------
// Kernel 0: fp32 -> bf16 converts: X inputs (grid.x 2048) and W matrices
// (grid.x 512) when workspace allows. grid=(2048, 3 or 7), block=256.
// ---------------------------------------------------------------------------
__global__ __launch_bounds__(256) void cvt_kernel(
    const float* __restrict__ q, const float* __restrict__ k, const float* __restrict__ v,
    const float* __restrict__ Wq, const float* __restrict__ Wk,
    const float* __restrict__ Wv, const float* __restrict__ Wo,
    unsigned short* __restrict__ xq, unsigned short* __restrict__ xk,
    unsigned short* __restrict__ xv, unsigned short* __restrict__ wbf)
{
    const int z = blockIdx.y;
    if (z >= 3 && blockIdx.x >= 512) return;
    const float* src; unsigned short* dst;
    switch (z) {
        case 0: src = q;  dst = xq; break;
        case 1: src = k;  dst = xk; break;
        case 2: src = v;  dst = xv; break;
        case 3: src = Wq; dst = wbf; break;
        case 4: src = Wk; dst = wbf + (size_t)E_*E_; break;
        case 5: src = Wv; dst = wbf + 2*(size_t)E_*E_; break;
        default: src = Wo; dst = wbf + 3*(size_t)E_*E_; break;
    }
    size_t i = ((size_t)blockIdx.x * 256 + threadIdx.x) * 8;
    f32x4 a = *(const f32x4*)(src + i);
    f32x4 c = *(const f32x4*)(src + i + 4);
    *(s16x8*)(dst + i) = cvt8(a, c);
}

// ---------------------------------------------------------------------------
// Kernel 1: QKV projections. 128x128 tile, BK=64, global_load_lds staging
// with XOR chunk swizzle. K output pre-scaled by 0.125*log2(e); V output
// stored f16, transposed + slot-permuted. grid=(8,32,3), block=256.
// ---------------------------------------------------------------------------
__global__ __launch_bounds__(256) void qkv_kernel(
    const unsigned short* __restrict__ xq, const unsigned short* __restrict__ xk,
    const unsigned short* __restrict__ xv,
    const unsigned short* __restrict__ wbf,
    const float* __restrict__ Wq, const float* __restrict__ Wk, const float* __restrict__ Wv,
    const float* __restrict__ bq, const float* __restrict__ bk, const float* __restrict__ bv,
    unsigned short* __restrict__ qkvout)
{
    const int z = blockIdx.z;
    const unsigned short* X  = (z==0) ? xq : (z==1) ? xk : xv;
    const float*          Bf = (z==0) ? Wq : (z==1) ? Wk : Wv;
    const float*        bias = (z==0) ? bq : (z==1) ? bk : bv;
    const unsigned short* Bbf = wbf ? (wbf + (size_t)z * E_ * E_) : nullptr;
    unsigned short* dst = qkvout + (size_t)z * PROJ_;

    __shared__ __align__(16) unsigned short As[128 * 64];
    __shared__ __align__(16) unsigned short Bs[128 * 64];

    const int t = threadIdx.x;
    const int lane = t & 63, w = t >> 6;
    const int quad = lane >> 4, l16 = lane & 15;
    const int wm = (w & 1) * 64, wn = (w >> 1) * 64;
    const int rowBase = blockIdx.y * 128, nBase = blockIdx.x * 128;

    const int r0 = t >> 3;                       // 0..31
    const int ch = ((t & 7) ^ (r0 & 7)) * 8;     // swizzled global chunk
    const unsigned short* gA  = X + (size_t)(rowBase + r0) * E_ + ch;
    const unsigned short* gBb = Bbf ? Bbf + (size_t)(nBase + r0) * E_ + ch : nullptr;
    const float*          gBf = Bf + (size_t)(nBase + r0) * E_ + ch;

    unsigned short* ldsA = &As[(size_t)w * 64 * 8];
    unsigned short* ldsB = &Bs[(size_t)w * 64 * 8];

    f32x4 acc[4][4] = {};

    for (int kk = 0; kk < E_; kk += 64) {
        __syncthreads();
        #pragma unroll
        for (int p = 0; p < 4; p++)
            gl16(gA + (size_t)(32 * p) * E_ + kk, ldsA + (size_t)p * 256 * 8);
        if (Bbf) {
            #pragma unroll
            for (int p = 0; p < 4; p++)
                gl16(gBb + (size_t)(32 * p) * E_ + kk, ldsB + (size_t)p * 256 * 8);
        } else {
            #pragma unroll
            for (int p = 0; p < 4; p++) {
                const float* gp = gBf + (size_t)(32 * p) * E_ + kk;
                f32x4 b0 = *(const f32x4*)gp;
                f32x4 b1 = *(const f32x4*)(gp + 4);
                *(s16x8*)&Bs[(size_t)(r0 + 32 * p) * 64 + (t & 7) * 8] = cvt8(b0, b1);
            }
        }
        __syncthreads();
        #pragma unroll
        for (int ko = 0; ko < 2; ko++) {
            bf16x8 af[4], bfr[4];
            #pragma unroll
            for (int im = 0; im < 4; im++) {
                int r = wm + im * 16 + l16;
                af[im] = *(const bf16x8*)&As[(size_t)r * 64 + (((ko * 4 + quad) ^ (l16 & 7)) * 8)];
            }
            #pragma unroll
            for (int in = 0; in < 4; in++) {
                int r = wn + in * 16 + l16;
                bfr[in] = *(const bf16x8*)&Bs[(size_t)r * 64 + (((ko * 4 + quad) ^ (l16 & 7)) * 8)];
            }
            #pragma unroll
            for (int im = 0; im < 4; im++)
                #pragma unroll
                for (int in = 0; in < 4; in++)
                    acc[im][in] = MFMA(af[im], bfr[in], acc[im][in]);
        }
    }

    // epilogue: bias, permute to (bh,s,d); K scaled; V -> f16 transposed+permuted
    #pragma unroll
    for (int im = 0; im < 4; im++)
      #pragma unroll
      for (int in = 0; in < 4; in++) {
        int col = nBase + wn + in * 16 + l16;       // h*64+d
        float bb = bias[col];
        int h = col >> 6, d = col & 63;
        #pragma unroll
        for (int r = 0; r < 4; r++) {
            int row = rowBase + wm + im * 16 + quad * 4 + r;   // b*S+s
            float val = acc[im][in][r] + bb;
            int b = row >> 11, s = row & 2047;
            size_t base = ((size_t)(b * H_ + h)) * ((size_t)S_ * D_);
            if (z == 0) {
                dst[base + (size_t)s * D_ + d] = f2bf(val);
            } else if (z == 1) {
                dst[base + (size_t)s * D_ + d] = f2bf(val * 0.1803368801111204f);
            } else {
                int k6 = s & 63;
                int slot = ((k6 >> 5) & 1) * 32 + ((k6 >> 2) & 3) * 8
                         + ((k6 >> 4) & 1) * 4 + (k6 & 3);
                _Float16 hv = (_Float16)val;
                dst[base + (size_t)d * S_ + (s & ~63) + slot] =
                    __builtin_bit_cast(unsigned short, hv);
            }
        }
      }
}

// ---------------------------------------------------------------------------
// Kernel 2: fused attention. grid=(32, 32), block=256 (4 waves x 16 queries).
// K pre-scaled, tile-uniform mask classes with split accumulators (e-factor
// applied at epilogue), denominator via ones-MFMA, f16 P/V, async staging.
// ---------------------------------------------------------------------------
__global__ __launch_bounds__(256) void attn_kernel(
    const unsigned short* __restrict__ qkvout, unsigned short* __restrict__ attnout)
{
    const int bh = blockIdx.y, b = bh >> 4, h = bh & 15;
    const int qbase = blockIdx.x * 64;
    const int t = threadIdx.x, w = t >> 6, lane = t & 63;
    const int quad = lane >> 4, l16 = lane & 15;

    const unsigned short* qg = qkvout + (size_t)bh * (S_ * D_);
    const unsigned short* kg = qkvout + PROJ_ + (size_t)bh * (S_ * D_);
    const unsigned short* vT = qkvout + 2 * PROJ_ + (size_t)bh * (S_ * D_);

    __shared__ __align__(16) unsigned short Ks [64 * 64];
    __shared__ __align__(16) unsigned short VTs[64 * 64];

    const int qi = qbase + w * 16 + l16;
    bf16x8 aq0 = *(const bf16x8*)&qg[(size_t)qi * 64 + quad * 8];
    bf16x8 aq1 = *(const bf16x8*)&qg[(size_t)qi * 64 + 32 + quad * 8];

    f32x4 Oi[4] = {}, Oo[4] = {};
    f32x4 Si = {}, So = {};

    const int r0 = t >> 3;
    const int ch = ((t & 7) ^ (r0 & 7)) * 8;
    unsigned short* ldsK = &Ks[(size_t)w * 64 * 8];
    unsigned short* ldsV = &VTs[(size_t)w * 64 * 8];

    f16x8 onesv;
    #pragma unroll
    for (int j = 0; j < 8; j++) onesv[j] = (_Float16)1.0f;

    for (int kt = 0; kt < S_; kt += 64) {
        __syncthreads();
        gl16(kg + (size_t)(kt + r0) * 64 + ch,      ldsK);
        gl16(kg + (size_t)(kt + r0 + 32) * 64 + ch, ldsK + 256 * 8);
        gl16(vT + (size_t)r0 * S_ + kt + ch,        ldsV);
        gl16(vT + (size_t)(r0 + 32) * S_ + kt + ch, ldsV + 256 * 8);
        __syncthreads();

        const int dq = qbase - kt;
        const int cls = (dq == 128 || dq == -128) ? 2 : (dq >= -64 && dq <= 64) ? 0 : 1;

        f32x4 p[4];
        #pragma unroll
        for (int sub = 0; sub < 4; sub++) {
            int row = sub * 16 + l16, sw = row & 7;
            bf16x8 bk0 = *(const bf16x8*)&Ks[(size_t)row * 64 + ((quad ^ sw) * 8)];
            bf16x8 bk1 = *(const bf16x8*)&Ks[(size_t)row * 64 + (((4 + quad) ^ sw) * 8)];
            f32x4 zz = {};
            zz = MFMA(bk0, aq0, zz);
            zz = MFMA(bk1, aq1, zz);
            if (cls == 2) {
                const int jb = kt + sub * 16 + quad * 4;
                #pragma unroll
                for (int r = 0; r < 4; r++) {
                    int di = qi - (jb + r); di = di < 0 ? -di : di;
                    p[sub][r] = exp2f(zz[r] + (di <= HALF_W ? 0.f : 1.44269504089f));
                }
            } else {
                #pragma unroll
                for (int r = 0; r < 4; r++) p[sub][r] = exp2f(zz[r]);
            }
        }

        // pack P to f16 A-fragments (2 scores per v_cvt_pkrtz)
        u32x4 u0, u1;
        u0[0] = __builtin_bit_cast(unsigned int, __builtin_amdgcn_cvt_pkrtz(p[0][0], p[0][1]));
        u0[1] = __builtin_bit_cast(unsigned int, __builtin_amdgcn_cvt_pkrtz(p[0][2], p[0][3]));
        u0[2] = __builtin_bit_cast(unsigned int, __builtin_amdgcn_cvt_pkrtz(p[1][0], p[1][1]));
        u0[3] = __builtin_bit_cast(unsigned int, __builtin_amdgcn_cvt_pkrtz(p[1][2], p[1][3]));
        u1[0] = __builtin_bit_cast(unsigned int, __builtin_amdgcn_cvt_pkrtz(p[2][0], p[2][1]));
        u1[1] = __builtin_bit_cast(unsigned int, __builtin_amdgcn_cvt_pkrtz(p[2][2], p[2][3]));
        u1[2] = __builtin_bit_cast(unsigned int, __builtin_amdgcn_cvt_pkrtz(p[3][0], p[3][1]));
        u1[3] = __builtin_bit_cast(unsigned int, __builtin_amdgcn_cvt_pkrtz(p[3][2], p[3][3]));
        f16x8 aP0 = __builtin_bit_cast(f16x8, u0);
        f16x8 aP1 = __builtin_bit_cast(f16x8, u1);

        if (cls == 1) {
            #pragma unroll
            for (int dt = 0; dt < 4; dt++) {
                int row = dt * 16 + l16, sw = row & 7;
                f16x8 v0 = *(const f16x8*)&VTs[(size_t)row * 64 + ((quad ^ sw) * 8)];
                f16x8 v1 = *(const f16x8*)&VTs[(size_t)row * 64 + (((4 + quad) ^ sw) * 8)];
                Oo[dt] = MFMAH(aP0, v0, Oo[dt]);
                Oo[dt] = MFMAH(aP1, v1, Oo[dt]);
            }
            So = MFMAH(aP0, onesv, So);
            So = MFMAH(aP1, onesv, So);
        } else {
            #pragma unroll
            for (int dt = 0; dt < 4; dt++) {
                int row = dt * 16 + l16, sw = row & 7;
                f16x8 v0 = *(const f16x8*)&VTs[(size_t)row * 64 + ((quad ^ sw) * 8)];
                f16x8 v1 = *(const f16x8*)&VTs[(size_t)row * 64 + (((4 + quad) ^ sw) * 8)];
                Oi[dt] = MFMAH(aP0, v0, Oi[dt]);
                Oi[dt] = MFMAH(aP1, v1, Oi[dt]);
            }
            Si = MFMAH(aP0, onesv, Si);
            Si = MFMAH(aP1, onesv, Si);
        }
    }

    const float E1 = 2.718281828459045f;
    float rd[4];
    #pragma unroll
    for (int r = 0; r < 4; r++) rd[r] = 1.0f / (Si[r] + E1 * So[r]);

    #pragma unroll
    for (int dt = 0; dt < 4; dt++)
        #pragma unroll
        for (int r = 0; r < 4; r++) {
            float oo = (Oi[dt][r] + E1 * Oo[dt][r]) * rd[r];
            int srow2 = qbase + w * 16 + quad * 4 + r;
            int col   = h * 64 + dt * 16 + l16;
            attnout[((size_t)(b * S_ + srow2)) * E_ + col] = f2bf(oo);
        }
}

// ---------------------------------------------------------------------------
// Kernel 3: output projection. 64x128 tile, BK=64, async staging.
// grid=(8,64), block=256, fp32 out.
// ---------------------------------------------------------------------------
__global__ __launch_bounds__(256) void oproj_kernel(
    const unsigned short* __restrict__ Aattn, const unsigned short* __restrict__ WoBf,
    const float* __restrict__ Wo, const float* __restrict__ bo, float* __restrict__ out)
{
    __shared__ __align__(16) unsigned short As[64 * 64];
    __shared__ __align__(16) unsigned short Bs[128 * 64];

    const int t = threadIdx.x;
    const int lane = t & 63, w = t >> 6;
    const int quad = lane >> 4, l16 = lane & 15;
    const int wm = (w & 1) * 32, wn = (w >> 1) * 64;
    const int rowBase = blockIdx.y * 64, nBase = blockIdx.x * 128;

    const int r0 = t >> 3;
    const int ch = ((t & 7) ^ (r0 & 7)) * 8;
    const unsigned short* gA  = Aattn + (size_t)(rowBase + r0) * E_ + ch;
    const unsigned short* gBb = WoBf ? WoBf + (size_t)(nBase + r0) * E_ + ch : nullptr;
    const float*          gBf = Wo + (size_t)(nBase + r0) * E_ + ch;

    unsigned short* ldsA = &As[(size_t)w * 64 * 8];
    unsigned short* ldsB = &Bs[(size_t)w * 64 * 8];

    f32x4 acc[2][4] = {};

    for (int kk = 0; kk < E_; kk += 64) {
        __syncthreads();
        gl16(gA + kk, ldsA);
        gl16(gA + (size_t)32 * E_ + kk, ldsA + 256 * 8);
        if (gBb) {
            #pragma unroll
            for (int p = 0; p < 4; p++)
                gl16(gBb + (size_t)(32 * p) * E_ + kk, ldsB + (size_t)p * 256 * 8);
        } else {
            #pragma unroll
            for (int p = 0; p < 4; p++) {
                const float* gp = gBf + (size_t)(32 * p) * E_ + kk;
                f32x4 b0 = *(const f32x4*)gp;
                f32x4 b1 = *(const f32x4*)(gp + 4);
                *(s16x8*)&Bs[(size_t)(r0 + 32 * p) * 64 + (t & 7) * 8] = cvt8(b0, b1);
            }
        }
        __syncthreads();
        #pragma unroll
        for (int ko = 0; ko < 2; ko++) {
            bf16x8 af[2], bfr[4];
            #pragma unroll
            for (int im = 0; im < 2; im++) {
                int r = wm + im * 16 + l16;
                af[im] = *(const bf16x8*)&As[(size_t)r * 64 + (((ko * 4 + quad) ^ (l16 & 7)) * 8)];
            }
            #pragma unroll
            for (int in = 0; in < 4; in++) {
                int r = wn + in * 16 + l16;
                bfr[in] = *(const bf16x8*)&Bs[(size_t)r * 64 + (((ko * 4 + quad) ^ (l16 & 7)) * 8)];
            }
            #pragma unroll
            for (int im = 0; im < 2; im++)
                #pragma unroll
                for (int in = 0; in < 4; in++)
                    acc[im][in] = MFMA(af[im], bfr[in], acc[im][in]);
        }
    }

    #pragma unroll
    for (int im = 0; im < 2; im++)
      #pragma unroll
      for (int in = 0; in < 4; in++) {
          int col = nBase + wn + in * 16 + l16;
          float bb = bo[col];
          #pragma unroll
          for (int r = 0; r < 4; r++) {
              int row = rowBase + wm + im * 16 + quad * 4 + r;
              out[(size_t)row * E_ + col] = acc[im][in][r] + bb;
          }
      }
}

// ---------------------------------------------------------------------------
extern "C" void kernel_launch(void* const* d_in, const int* in_sizes, int n_in,
                              void* d_out, int out_size, void* d_ws, size_t ws_size,
                              hipStream_t stream) {
    const float* query = (const float*)d_in[0];
    const float* key_  = (const float*)d_in[1];
    const float* value = (const float*)d_in[2];
    const float* Wq = (const float*)d_in[3];
    const float* bq = (const float*)d_in[4];
    const float* Wk = (const float*)d_in[5];
    const float* bk = (const float*)d_in[6];
    const float* Wv = (const float*)d_in[7];
    const float* bv = (const float*)d_in[8];
    const float* Wo = (const float*)d_in[9];
    const float* bo = (const float*)d_in[10];

    unsigned short* ws      = (unsigned short*)d_ws;
    unsigned short* xv      = ws;                    // PROJ_ (dead after qkv)
    unsigned short* attnout = ws;                    // reuses xv region
    unsigned short* qkvout  = ws + PROJ_;            // 3*PROJ_
    size_t needB = (4 * PROJ_ + 4 * (size_t)E_ * E_) * 2;
    unsigned short* wbf = (ws_size >= needB) ? (ws + 4 * PROJ_) : nullptr;
    unsigned short* xq = (unsigned short*)d_out;     // scratch until oproj
    unsigned short* xk = xq + PROJ_;

    cvt_kernel<<<dim3(2048, wbf ? 7 : 3), 256, 0, stream>>>(
        query, key_, value, Wq, Wk, Wv, Wo, xq, xk, xv, wbf);
    qkv_kernel<<<dim3(8, 32, 3), 256, 0, stream>>>(
        xq, xk, xv, wbf, Wq, Wk, Wv, bq, bk, bv, qkvout);
    attn_kernel<<<dim3(32, 32), 256, 0, stream>>>(qkvout, attnout);
    oproj_kernel<<<dim3(8, 64), 256, 0, stream>>>(
        attnout, wbf ? wbf + 3 * (size_t)E_ * E_ : nullptr, Wo, bo, (float*)d_out);
}

// Round 6
// 250.033 us; speedup vs baseline: 1.6230x; 1.0831x over previous
//
#include <hip/hip_runtime.h>
#include <stdint.h>

#define B_ 2
#define S_ 2048
#define E_ 1024
#define H_ 16
#define D_ 64
#define M_ (B_*S_)
#define PROJ_ ((size_t)M_*E_)
#define HALF_W 128

typedef float    f32x4 __attribute__((ext_vector_type(4)));
typedef short    s16x8 __attribute__((ext_vector_type(8)));
typedef __bf16   bf16x8 __attribute__((ext_vector_type(8)));
typedef _Float16 f16x8 __attribute__((ext_vector_type(8)));
typedef unsigned int u32x4 __attribute__((ext_vector_type(4)));

typedef const __attribute__((address_space(1))) void* gas_t;
typedef __attribute__((address_space(3))) void*       las_t;

__device__ __forceinline__ void gl16(const void* g, void* l) {
    __builtin_amdgcn_global_load_lds((gas_t)g, (las_t)l, 16, 0, 0);
}

__device__ __forceinline__ f32x4 MFMA(bf16x8 a, bf16x8 b, f32x4 c) {
    return __builtin_amdgcn_mfma_f32_16x16x32_bf16(a, b, c, 0, 0, 0);
}
__device__ __forceinline__ f32x4 MFMAH(f16x8 a, f16x8 b, f32x4 c) {
    return __builtin_amdgcn_mfma_f32_16x16x32_f16(a, b, c, 0, 0, 0);
}

__device__ __forceinline__ unsigned short f2bf(float f) {
    union { float f; unsigned int u; } x; x.f = f;
    unsigned int u = x.u + 0x7FFFu + ((x.u >> 16) & 1u);
    return (unsigned short)(u >> 16);
}

__device__ __forceinline__ s16x8 cvt8(f32x4 a, f32x4 b) {
    s16x8 h;
    h[0]=(short)f2bf(a[0]); h[1]=(short)f2bf(a[1]); h[2]=(short)f2bf(a[2]); h[3]=(short)f2bf(a[3]);
    h[4]=(short)f2bf(b[0]); h[5]=(short)f2bf(b[1]); h[6]=(short)f2bf(b[2]); h[7]=(short)f2bf(b[3]);
    return h;
}

// ---------------------------------------------------------------------------
// Kernel 0: fp32 -> bf16 converts (X inputs; W matrices when ws allows).
// ---------------------------------------------------------------------------
__global__ __launch_bounds__(256) void cvt_kernel(
    const float* __restrict__ q, const float* __restrict__ k, const float* __restrict__ v,
    const float* __restrict__ Wq, const float* __restrict__ Wk,
    const float* __restrict__ Wv, const float* __restrict__ Wo,
    unsigned short* __restrict__ xq, unsigned short* __restrict__ xk,
    unsigned short* __restrict__ xv, unsigned short* __restrict__ wbf)
{
    const int z = blockIdx.y;
    if (z >= 3 && blockIdx.x >= 512) return;
    const float* src; unsigned short* dst;
    switch (z) {
        case 0: src = q;  dst = xq; break;
        case 1: src = k;  dst = xk; break;
        case 2: src = v;  dst = xv; break;
        case 3: src = Wq; dst = wbf; break;
        case 4: src = Wk; dst = wbf + (size_t)E_*E_; break;
        case 5: src = Wv; dst = wbf + 2*(size_t)E_*E_; break;
        default: src = Wo; dst = wbf + 3*(size_t)E_*E_; break;
    }
    size_t i = ((size_t)blockIdx.x * 256 + threadIdx.x) * 8;
    f32x4 a = *(const f32x4*)(src + i);
    f32x4 c = *(const f32x4*)(src + i + 4);
    *(s16x8*)(dst + i) = cvt8(a, c);
}

// ---------------------------------------------------------------------------
// Kernel 1: QKV projections. 128x128 tile, BK=32, LDS double-buffered async
// staging (1 barrier/stage). K pre-scaled; V stored f16 transposed+permuted.
// grid=(8,32,3), block=256.
// ---------------------------------------------------------------------------
__global__ __launch_bounds__(256, 2) void qkv_kernel(
    const unsigned short* __restrict__ xq, const unsigned short* __restrict__ xk,
    const unsigned short* __restrict__ xv,
    const unsigned short* __restrict__ wbf,
    const float* __restrict__ Wq, const float* __restrict__ Wk, const float* __restrict__ Wv,
    const float* __restrict__ bq, const float* __restrict__ bk, const float* __restrict__ bv,
    unsigned short* __restrict__ qkvout)
{
    const int z = blockIdx.z;
    const unsigned short* X  = (z==0) ? xq : (z==1) ? xk : xv;
    const float*          Bf = (z==0) ? Wq : (z==1) ? Wk : Wv;
    const float*        bias = (z==0) ? bq : (z==1) ? bk : bv;
    const unsigned short* Bbf = wbf ? (wbf + (size_t)z * E_ * E_) : nullptr;
    unsigned short* dst = qkvout + (size_t)z * PROJ_;

    __shared__ __align__(16) unsigned short As[2][128 * 32];
    __shared__ __align__(16) unsigned short Bs[2][128 * 32];

    const int t = threadIdx.x;
    const int lane = t & 63, w = t >> 6;
    const int quad = lane >> 4, l16 = lane & 15;
    const int wm = (w & 1) * 64, wn = (w >> 1) * 64;
    const int rowBase = blockIdx.y * 128, nBase = blockIdx.x * 128;

    const int r0 = t >> 2;                    // 0..63
    const int c4 = (t & 3) ^ (r0 & 3);        // swizzled chunk
    const unsigned short* gA  = X + (size_t)(rowBase + r0) * E_ + c4 * 8;
    const unsigned short* gBb = Bbf ? Bbf + (size_t)(nBase + r0) * E_ + c4 * 8 : nullptr;
    const float*          gBf = Bf + (size_t)(nBase + r0) * E_ + c4 * 8;

    f32x4 acc[4][4] = {};

    auto issue = [&](int kk, int pb) {
        unsigned short* dA = &As[pb][(size_t)w * 512];
        gl16(gA + kk, dA);
        gl16(gA + (size_t)64 * E_ + kk, dA + 2048);
        if (gBb) {
            unsigned short* dB = &Bs[pb][(size_t)w * 512];
            gl16(gBb + kk, dB);
            gl16(gBb + (size_t)64 * E_ + kk, dB + 2048);
        } else {
            const float* gp0 = gBf + kk;
            const float* gp1 = gBf + (size_t)64 * E_ + kk;
            f32x4 a0 = *(const f32x4*)gp0, a1 = *(const f32x4*)(gp0 + 4);
            f32x4 b0 = *(const f32x4*)gp1, b1 = *(const f32x4*)(gp1 + 4);
            *(s16x8*)&Bs[pb][(size_t)r0 * 32 + (t & 3) * 8]        = cvt8(a0, a1);
            *(s16x8*)&Bs[pb][(size_t)(r0 + 64) * 32 + (t & 3) * 8] = cvt8(b0, b1);
        }
    };

    issue(0, 0);
    __syncthreads();

    for (int s = 0; s < 32; s++) {
        const int pb = s & 1;
        if (s < 31) issue((s + 1) * 32, pb ^ 1);

        bf16x8 af[4], bfr[4];
        #pragma unroll
        for (int im = 0; im < 4; im++) {
            int r = wm + im * 16 + l16;
            af[im] = *(const bf16x8*)&As[pb][(size_t)r * 32 + ((quad ^ (l16 & 3)) * 8)];
        }
        #pragma unroll
        for (int in = 0; in < 4; in++) {
            int r = wn + in * 16 + l16;
            bfr[in] = *(const bf16x8*)&Bs[pb][(size_t)r * 32 + ((quad ^ (l16 & 3)) * 8)];
        }
        #pragma unroll
        for (int im = 0; im < 4; im++)
            #pragma unroll
            for (int in = 0; in < 4; in++)
                acc[im][in] = MFMA(af[im], bfr[in], acc[im][in]);
        __syncthreads();
    }

    // epilogue: bias, permute; K scaled by 0.125*log2(e); V f16 transposed+permuted
    #pragma unroll
    for (int im = 0; im < 4; im++)
      #pragma unroll
      for (int in = 0; in < 4; in++) {
        int col = nBase + wn + in * 16 + l16;       // h*64+d
        float bb = bias[col];
        int h = col >> 6, d = col & 63;
        #pragma unroll
        for (int r = 0; r < 4; r++) {
            int row = rowBase + wm + im * 16 + quad * 4 + r;   // b*S+s
            float val = acc[im][in][r] + bb;
            int b = row >> 11, s = row & 2047;
            size_t base = ((size_t)(b * H_ + h)) * ((size_t)S_ * D_);
            if (z == 0) {
                dst[base + (size_t)s * D_ + d] = f2bf(val);
            } else if (z == 1) {
                dst[base + (size_t)s * D_ + d] = f2bf(val * 0.1803368801111204f);
            } else {
                int k6 = s & 63;
                int slot = ((k6 >> 5) & 1) * 32 + ((k6 >> 2) & 3) * 8
                         + ((k6 >> 4) & 1) * 4 + (k6 & 3);
                _Float16 hv = (_Float16)val;
                dst[base + (size_t)d * S_ + (s & ~63) + slot] =
                    __builtin_bit_cast(unsigned short, hv);
            }
        }
      }
}

// ---------------------------------------------------------------------------
// Kernel 2: fused attention. grid=(16,32), block=256. 128 q/block, 32 q/wave
// (2 groups of 16): K/V LDS reads shared across groups. LDS double-buffered,
// 1 barrier/tile. Tile-uniform mask classes, split accumulators, ones-MFMA
// denominator, f16 P/V.
// ---------------------------------------------------------------------------
__global__ __launch_bounds__(256, 2) void attn_kernel(
    const unsigned short* __restrict__ qkvout, unsigned short* __restrict__ attnout)
{
    const int bh = blockIdx.y, b = bh >> 4, h = bh & 15;
    const int qbase = blockIdx.x * 128;
    const int t = threadIdx.x, w = t >> 6, lane = t & 63;
    const int quad = lane >> 4, l16 = lane & 15;

    const unsigned short* qg = qkvout + (size_t)bh * (S_ * D_);
    const unsigned short* kg = qkvout + PROJ_ + (size_t)bh * (S_ * D_);
    const unsigned short* vT = qkvout + 2 * PROJ_ + (size_t)bh * (S_ * D_);

    __shared__ __align__(16) unsigned short Ks [2][64 * 64];
    __shared__ __align__(16) unsigned short VTs[2][64 * 64];

    const int qi0 = qbase + w * 32 + l16;     // group 0 query
    const int qi1 = qi0 + 16;                 // group 1 query
    bf16x8 aq[2][2];
    aq[0][0] = *(const bf16x8*)&qg[(size_t)qi0 * 64 + quad * 8];
    aq[0][1] = *(const bf16x8*)&qg[(size_t)qi0 * 64 + 32 + quad * 8];
    aq[1][0] = *(const bf16x8*)&qg[(size_t)qi1 * 64 + quad * 8];
    aq[1][1] = *(const bf16x8*)&qg[(size_t)qi1 * 64 + 32 + quad * 8];

    f32x4 Oi[2][4] = {}, Oo[2][4] = {};
    f32x4 Si[2] = {}, So[2] = {};

    const int r0 = t >> 3;
    const int ch = ((t & 7) ^ (r0 & 7)) * 8;

    f16x8 onesv;
    #pragma unroll
    for (int j = 0; j < 8; j++) onesv[j] = (_Float16)1.0f;

    auto issue = [&](int kt, int pb) {
        unsigned short* dK = &Ks [pb][(size_t)w * 512];
        unsigned short* dV = &VTs[pb][(size_t)w * 512];
        gl16(kg + (size_t)(kt + r0) * 64 + ch,      dK);
        gl16(kg + (size_t)(kt + r0 + 32) * 64 + ch, dK + 2048);
        gl16(vT + (size_t)r0 * S_ + kt + ch,        dV);
        gl16(vT + (size_t)(r0 + 32) * S_ + kt + ch, dV + 2048);
    };

    issue(0, 0);
    __syncthreads();

    for (int s = 0; s < 32; s++) {
        const int pb = s & 1;
        const int kt = s * 64;
        if (s < 31) issue(kt + 64, pb ^ 1);

        const int dq = qbase - kt;
        const int cls = (dq == 0 || dq == -64) ? 0
                      : (dq >= 192 || dq <= -256) ? 1 : 2;

        f32x4 pp[2][4];
        const int sw = l16 & 7;
        #pragma unroll
        for (int sub = 0; sub < 4; sub++) {
            int row = sub * 16 + l16;
            bf16x8 bk0 = *(const bf16x8*)&Ks[pb][(size_t)row * 64 + ((quad ^ sw) * 8)];
            bf16x8 bk1 = *(const bf16x8*)&Ks[pb][(size_t)row * 64 + (((4 + quad) ^ sw) * 8)];
            #pragma unroll
            for (int g = 0; g < 2; g++) {
                f32x4 zz = {};
                zz = MFMA(bk0, aq[g][0], zz);
                zz = MFMA(bk1, aq[g][1], zz);
                if (cls == 2) {
                    const int jb = kt + sub * 16 + quad * 4;
                    const int qi = (g == 0) ? qi0 : qi1;
                    #pragma unroll
                    for (int r = 0; r < 4; r++) {
                        int di = qi - (jb + r); di = di < 0 ? -di : di;
                        pp[g][sub][r] = exp2f(zz[r] + (di <= HALF_W ? 0.f : 1.44269504089f));
                    }
                } else {
                    #pragma unroll
                    for (int r = 0; r < 4; r++) pp[g][sub][r] = exp2f(zz[r]);
                }
            }
        }

        // pack P to f16 A-fragments
        f16x8 aP[2][2];
        #pragma unroll
        for (int g = 0; g < 2; g++) {
            u32x4 u0, u1;
            u0[0] = __builtin_bit_cast(unsigned int, __builtin_amdgcn_cvt_pkrtz(pp[g][0][0], pp[g][0][1]));
            u0[1] = __builtin_bit_cast(unsigned int, __builtin_amdgcn_cvt_pkrtz(pp[g][0][2], pp[g][0][3]));
            u0[2] = __builtin_bit_cast(unsigned int, __builtin_amdgcn_cvt_pkrtz(pp[g][1][0], pp[g][1][1]));
            u0[3] = __builtin_bit_cast(unsigned int, __builtin_amdgcn_cvt_pkrtz(pp[g][1][2], pp[g][1][3]));
            u1[0] = __builtin_bit_cast(unsigned int, __builtin_amdgcn_cvt_pkrtz(pp[g][2][0], pp[g][2][1]));
            u1[1] = __builtin_bit_cast(unsigned int, __builtin_amdgcn_cvt_pkrtz(pp[g][2][2], pp[g][2][3]));
            u1[2] = __builtin_bit_cast(unsigned int, __builtin_amdgcn_cvt_pkrtz(pp[g][3][0], pp[g][3][1]));
            u1[3] = __builtin_bit_cast(unsigned int, __builtin_amdgcn_cvt_pkrtz(pp[g][3][2], pp[g][3][3]));
            aP[g][0] = __builtin_bit_cast(f16x8, u0);
            aP[g][1] = __builtin_bit_cast(f16x8, u1);
        }

        if (cls == 1) {
            #pragma unroll
            for (int dt = 0; dt < 4; dt++) {
                int row = dt * 16 + l16;
                f16x8 v0 = *(const f16x8*)&VTs[pb][(size_t)row * 64 + ((quad ^ sw) * 8)];
                f16x8 v1 = *(const f16x8*)&VTs[pb][(size_t)row * 64 + (((4 + quad) ^ sw) * 8)];
                #pragma unroll
                for (int g = 0; g < 2; g++) {
                    Oo[g][dt] = MFMAH(aP[g][0], v0, Oo[g][dt]);
                    Oo[g][dt] = MFMAH(aP[g][1], v1, Oo[g][dt]);
                }
            }
            #pragma unroll
            for (int g = 0; g < 2; g++) {
                So[g] = MFMAH(aP[g][0], onesv, So[g]);
                So[g] = MFMAH(aP[g][1], onesv, So[g]);
            }
        } else {
            #pragma unroll
            for (int dt = 0; dt < 4; dt++) {
                int row = dt * 16 + l16;
                f16x8 v0 = *(const f16x8*)&VTs[pb][(size_t)row * 64 + ((quad ^ sw) * 8)];
                f16x8 v1 = *(const f16x8*)&VTs[pb][(size_t)row * 64 + (((4 + quad) ^ sw) * 8)];
                #pragma unroll
                for (int g = 0; g < 2; g++) {
                    Oi[g][dt] = MFMAH(aP[g][0], v0, Oi[g][dt]);
                    Oi[g][dt] = MFMAH(aP[g][1], v1, Oi[g][dt]);
                }
            }
            #pragma unroll
            for (int g = 0; g < 2; g++) {
                Si[g] = MFMAH(aP[g][0], onesv, Si[g]);
                Si[g] = MFMAH(aP[g][1], onesv, Si[g]);
            }
        }
        __syncthreads();
    }

    const float E1 = 2.718281828459045f;
    #pragma unroll
    for (int g = 0; g < 2; g++) {
        float rd[4];
        #pragma unroll
        for (int r = 0; r < 4; r++) rd[r] = 1.0f / (Si[g][r] + E1 * So[g][r]);
        #pragma unroll
        for (int dt = 0; dt < 4; dt++)
            #pragma unroll
            for (int r = 0; r < 4; r++) {
                float oo = (Oi[g][dt][r] + E1 * Oo[g][dt][r]) * rd[r];
                int srow2 = qbase + w * 32 + g * 16 + quad * 4 + r;
                int col   = h * 64 + dt * 16 + l16;
                attnout[((size_t)(b * S_ + srow2)) * E_ + col] = f2bf(oo);
            }
    }
}

// ---------------------------------------------------------------------------
// Kernel 3: output projection. 64x128 tile, BK=32, dbuf async staging.
// grid=(8,64), block=256, fp32 out.
// ---------------------------------------------------------------------------
__global__ __launch_bounds__(256, 2) void oproj_kernel(
    const unsigned short* __restrict__ Aattn, const unsigned short* __restrict__ WoBf,
    const float* __restrict__ Wo, const float* __restrict__ bo, float* __restrict__ out)
{
    __shared__ __align__(16) unsigned short As[2][64 * 32];
    __shared__ __align__(16) unsigned short Bs[2][128 * 32];

    const int t = threadIdx.x;
    const int lane = t & 63, w = t >> 6;
    const int quad = lane >> 4, l16 = lane & 15;
    const int wm = (w & 1) * 32, wn = (w >> 1) * 64;
    const int rowBase = blockIdx.y * 64, nBase = blockIdx.x * 128;

    const int r0 = t >> 2;
    const int c4 = (t & 3) ^ (r0 & 3);
    const unsigned short* gA  = Aattn + (size_t)(rowBase + r0) * E_ + c4 * 8;
    const unsigned short* gBb = WoBf ? WoBf + (size_t)(nBase + r0) * E_ + c4 * 8 : nullptr;
    const float*          gBf = Wo + (size_t)(nBase + r0) * E_ + c4 * 8;

    f32x4 acc[2][4] = {};

    auto issue = [&](int kk, int pb) {
        gl16(gA + kk, &As[pb][(size_t)w * 512]);
        if (gBb) {
            unsigned short* dB = &Bs[pb][(size_t)w * 512];
            gl16(gBb + kk, dB);
            gl16(gBb + (size_t)64 * E_ + kk, dB + 2048);
        } else {
            const float* gp0 = gBf + kk;
            const float* gp1 = gBf + (size_t)64 * E_ + kk;
            f32x4 a0 = *(const f32x4*)gp0, a1 = *(const f32x4*)(gp0 + 4);
            f32x4 b0 = *(const f32x4*)gp1, b1 = *(const f32x4*)(gp1 + 4);
            *(s16x8*)&Bs[pb][(size_t)r0 * 32 + (t & 3) * 8]        = cvt8(a0, a1);
            *(s16x8*)&Bs[pb][(size_t)(r0 + 64) * 32 + (t & 3) * 8] = cvt8(b0, b1);
        }
    };

    issue(0, 0);
    __syncthreads();

    for (int s = 0; s < 32; s++) {
        const int pb = s & 1;
        if (s < 31) issue((s + 1) * 32, pb ^ 1);

        bf16x8 af[2], bfr[4];
        #pragma unroll
        for (int im = 0; im < 2; im++) {
            int r = wm + im * 16 + l16;
            af[im] = *(const bf16x8*)&As[pb][(size_t)r * 32 + ((quad ^ (l16 & 3)) * 8)];
        }
        #pragma unroll
        for (int in = 0; in < 4; in++) {
            int r = wn + in * 16 + l16;
            bfr[in] = *(const bf16x8*)&Bs[pb][(size_t)r * 32 + ((quad ^ (l16 & 3)) * 8)];
        }
        #pragma unroll
        for (int im = 0; im < 2; im++)
            #pragma unroll
            for (int in = 0; in < 4; in++)
                acc[im][in] = MFMA(af[im], bfr[in], acc[im][in]);
        __syncthreads();
    }

    #pragma unroll
    for (int im = 0; im < 2; im++)
      #pragma unroll
      for (int in = 0; in < 4; in++) {
          int col = nBase + wn + in * 16 + l16;
          float bb = bo[col];
          #pragma unroll
          for (int r = 0; r < 4; r++) {
              int row = rowBase + wm + im * 16 + quad * 4 + r;
              out[(size_t)row * E_ + col] = acc[im][in][r] + bb;
          }
      }
}

// ---------------------------------------------------------------------------
extern "C" void kernel_launch(void* const* d_in, const int* in_sizes, int n_in,
                              void* d_out, int out_size, void* d_ws, size_t ws_size,
                              hipStream_t stream) {
    const float* query = (const float*)d_in[0];
    const float* key_  = (const float*)d_in[1];
    const float* value = (const float*)d_in[2];
    const float* Wq = (const float*)d_in[3];
    const float* bq = (const float*)d_in[4];
    const float* Wk = (const float*)d_in[5];
    const float* bk = (const float*)d_in[6];
    const float* Wv = (const float*)d_in[7];
    const float* bv = (const float*)d_in[8];
    const float* Wo = (const float*)d_in[9];
    const float* bo = (const float*)d_in[10];

    unsigned short* ws      = (unsigned short*)d_ws;
    unsigned short* xv      = ws;                    // PROJ_ (dead after qkv)
    unsigned short* attnout = ws;                    // reuses xv region
    unsigned short* qkvout  = ws + PROJ_;            // 3*PROJ_
    size_t needB = (4 * PROJ_ + 4 * (size_t)E_ * E_) * 2;
    unsigned short* wbf = (ws_size >= needB) ? (ws + 4 * PROJ_) : nullptr;
    unsigned short* xq = (unsigned short*)d_out;     // scratch until oproj
    unsigned short* xk = xq + PROJ_;

    cvt_kernel<<<dim3(2048, wbf ? 7 : 3), 256, 0, stream>>>(
        query, key_, value, Wq, Wk, Wv, Wo, xq, xk, xv, wbf);
    qkv_kernel<<<dim3(8, 32, 3), 256, 0, stream>>>(
        xq, xk, xv, wbf, Wq, Wk, Wv, bq, bk, bv, qkvout);
    attn_kernel<<<dim3(16, 32), 256, 0, stream>>>(qkvout, attnout);
    oproj_kernel<<<dim3(8, 64), 256, 0, stream>>>(
        attnout, wbf ? wbf + 3 * (size_t)E_ * E_ : nullptr, Wo, bo, (float*)d_out);
}